// Round 2
// 229.857 us; speedup vs baseline: 1.0101x; 1.0101x over previous
//
#include <hip/hip_runtime.h>
#include <hip/hip_bf16.h>

// GCN backbone, bf16 datapath:
//   layer: g = h@W (MFMA bf16, f32 acc, bf16 out); h' = relu(csr_agg(g)+b)
// CSR: u16 col entries (N < 65536), no self-loops (analytic self term),
// slots from count pass, rebuilt every call. Agg gathers bypass L1 via sc0.
// Fusions: zero+prepW in one launch; layer-1 GEMM + CSR count in one launch
// (independent work hides the ~41us atomic window).
// Agg: 64-edge register staging (cols+coefs via shfl), 16-wide gather batches
// with ONE vmcnt(0) drain per 16 edges; chunk-0 gathers issued before the
// dinv coef gathers so the two latency windows overlap. Single-buffered asm
// outputs, no occupancy cap (avoids the spill-before-waitcnt hazard that
// broke round 1).

#define TPB 256
typedef unsigned short u16;
typedef unsigned int u32;
typedef __attribute__((ext_vector_type(8))) __bf16 bf16x8;
typedef __attribute__((ext_vector_type(8))) u16 u16x8;
typedef __attribute__((ext_vector_type(4))) float f32x4;

__device__ __forceinline__ u16 f2b(float f) {
    __bf16 b = (__bf16)f;                 // RNE on gfx950
    return __builtin_bit_cast(u16, b);
}
__device__ __forceinline__ float b2f_lo(u32 w) { return __builtin_bit_cast(float, w << 16); }
__device__ __forceinline__ float b2f_hi(u32 w) { return __builtin_bit_cast(float, w & 0xffff0000u); }

__device__ __forceinline__ bf16x8 cvt8(float4 u0, float4 u1) {
    u16x8 r;
    r[0] = f2b(u0.x); r[1] = f2b(u0.y); r[2] = f2b(u0.z); r[3] = f2b(u0.w);
    r[4] = f2b(u1.x); r[5] = f2b(u1.y); r[6] = f2b(u1.z); r[7] = f2b(u1.w);
    return __builtin_bit_cast(bf16x8, r);
}

// ---------------- CSR build pieces ----------------
__device__ __forceinline__ void countslot_body(int bid, const int* __restrict__ dst,
                                               int* cnt, u16* __restrict__ aux, int E) {
    int e = (bid * TPB + (int)threadIdx.x) * 4;
    if (e + 3 < E) {
        int4 d = *(const int4*)(dst + e);
        ushort4 a;
        a.x = (u16)atomicAdd(&cnt[d.x], 1);
        a.y = (u16)atomicAdd(&cnt[d.y], 1);
        a.z = (u16)atomicAdd(&cnt[d.z], 1);
        a.w = (u16)atomicAdd(&cnt[d.w], 1);
        *(ushort4*)(aux + e) = a;
    } else {
        for (; e < E; ++e) aux[e] = (u16)atomicAdd(&cnt[dst[e]], 1);
    }
}

__global__ __launch_bounds__(TPB) void k_scan1(const int* __restrict__ cnt, int* rowptr,
                                               int* bsum, int N) {
    __shared__ int tmp[TPB];
    int t = threadIdx.x;
    int i = blockIdx.x * TPB + t;
    int v = (i < N) ? cnt[i] : 0;
    tmp[t] = v;
    __syncthreads();
    for (int off = 1; off < TPB; off <<= 1) {
        int y = (t >= off) ? tmp[t - off] : 0;
        __syncthreads();
        tmp[t] += y;
        __syncthreads();
    }
    if (i < N) rowptr[i] = tmp[t] - v;
    if (t == TPB - 1) bsum[blockIdx.x] = tmp[t];
}

__global__ __launch_bounds__(TPB) void k_scan2(int* bsum, int nb) {
    __shared__ int tmp[TPB];
    int t = threadIdx.x;
    int v = (t < nb) ? bsum[t] : 0;
    tmp[t] = v;
    __syncthreads();
    for (int off = 1; off < TPB; off <<= 1) {
        int y = (t >= off) ? tmp[t - off] : 0;
        __syncthreads();
        tmp[t] += y;
        __syncthreads();
    }
    if (t < nb) bsum[t] = tmp[t] - v;
}

__global__ __launch_bounds__(TPB) void k_scan3(int* rowptr, const int* __restrict__ bsum,
                                               const int* __restrict__ cnt, float* dinv,
                                               int N, int total) {
    int i = blockIdx.x * TPB + threadIdx.x;
    if (i < N) {
        rowptr[i] += bsum[blockIdx.x];
        dinv[i] = 1.0f / sqrtf((float)(cnt[i] + 1));  // +1 self-loop
    }
    if (i == 0) rowptr[N] = total;
}

__global__ __launch_bounds__(TPB) void k_fill(const int* __restrict__ src,
                                              const int* __restrict__ dst,
                                              const int* __restrict__ rowptr,
                                              const u16* __restrict__ aux,
                                              u16* __restrict__ cols, int E) {
    int e = (blockIdx.x * TPB + threadIdx.x) * 4;
    if (e + 3 < E) {
        int4 s = *(const int4*)(src + e);
        int4 d = *(const int4*)(dst + e);
        ushort4 a = *(const ushort4*)(aux + e);
        cols[rowptr[d.x] + a.x] = (u16)s.x;
        cols[rowptr[d.y] + a.y] = (u16)s.y;
        cols[rowptr[d.z] + a.z] = (u16)s.z;
        cols[rowptr[d.w] + a.w] = (u16)s.w;
    } else {
        for (; e < E; ++e) cols[rowptr[dst[e]] + aux[e]] = (u16)src[e];
    }
}

// W[128][128] f32 (k-major) -> Wt bf16 transposed + chunk-XOR-swizzled.
__device__ __forceinline__ void prepw_body(int bb, const float* __restrict__ Wa,
                                           const float* __restrict__ Wb,
                                           const float* __restrict__ Wc,
                                           u16* __restrict__ Wta, u16* __restrict__ Wtb,
                                           u16* __restrict__ Wtc) {
    int m = bb >> 3;
    const float* W = m == 0 ? Wa : (m == 1 ? Wb : Wc);
    u16* Wt = m == 0 ? Wta : (m == 1 ? Wtb : Wtc);
    int t = (bb & 7) * TPB + (int)threadIdx.x;
    int n = t >> 4, c = t & 15;
    u16x8 r;
#pragma unroll
    for (int j = 0; j < 8; ++j) r[j] = f2b(W[(8 * c + j) * 128 + n]);
    int cs = c ^ (n & 15);
    *(u16x8*)(Wt + n * 128 + cs * 8) = r;
}

// fused: blocks [0,nbZ) zero cnt; blocks [nbZ, nbZ+24) prep the 3 W matrices
__global__ __launch_bounds__(TPB) void k_zero_prep(int* cnt, int N, int nbZ,
                                                   const float* __restrict__ Wa,
                                                   const float* __restrict__ Wb,
                                                   const float* __restrict__ Wc,
                                                   u16* __restrict__ Wta,
                                                   u16* __restrict__ Wtb,
                                                   u16* __restrict__ Wtc) {
    int b = blockIdx.x;
    if (b < nbZ) {
        int i = b * TPB + threadIdx.x;
        if (i < N) cnt[i] = 0;
    } else {
        prepw_body(b - nbZ, Wa, Wb, Wc, Wta, Wtb, Wtc);
    }
}

// ---------------- MFMA GEMM: C[N][128] = A[N][128] @ W ----------------
template <bool F32IN>
__device__ __forceinline__ void gemm_body(int bid, const void* __restrict__ Ain,
                                          const u16* __restrict__ Wt,
                                          u16* __restrict__ C, int N) {
    __shared__ u16 Ws[128 * 128];  // 32 KB, pre-swizzled chunks
    int t = threadIdx.x;
    {
        const uint4* s = (const uint4*)Wt;
        uint4* d = (uint4*)Ws;
#pragma unroll
        for (int i = 0; i < 8; ++i) d[t + 256 * i] = s[t + 256 * i];
    }
    __syncthreads();
    int wave = t >> 6, lane = t & 63;
    int li = lane & 15, lq = lane >> 4;
    int r0 = bid * 128 + wave * 32;
    f32x4 acc[2][8];
#pragma unroll
    for (int i = 0; i < 2; ++i)
#pragma unroll
        for (int f = 0; f < 8; ++f) acc[i][f] = (f32x4){0.f, 0.f, 0.f, 0.f};

    int ra = r0 + li, rb = ra + 16;
    size_t ra_c = (size_t)(ra < N ? ra : N - 1);
    size_t rb_c = (size_t)(rb < N ? rb : N - 1);
#pragma unroll
    for (int kc = 0; kc < 4; ++kc) {
        int koff = 32 * kc + 8 * lq;
        bf16x8 a0, a1;
        if constexpr (F32IN) {
            const float* A = (const float*)Ain;
            const float4* p0 = (const float4*)(A + ra_c * 128 + koff);
            const float4* p1 = (const float4*)(A + rb_c * 128 + koff);
            a0 = cvt8(p0[0], p0[1]);
            a1 = cvt8(p1[0], p1[1]);
        } else {
            const u16* A = (const u16*)Ain;
            a0 = *(const bf16x8*)(A + ra_c * 128 + koff);
            a1 = *(const bf16x8*)(A + rb_c * 128 + koff);
        }
#pragma unroll
        for (int f = 0; f < 8; ++f) {
            int n = 16 * f + li;
            int chunk = (4 * kc + lq) ^ li;  // n&15 == li
            bf16x8 b = *(const bf16x8*)(Ws + n * 128 + chunk * 8);
            acc[0][f] = __builtin_amdgcn_mfma_f32_16x16x32_bf16(a0, b, acc[0][f], 0, 0, 0);
            acc[1][f] = __builtin_amdgcn_mfma_f32_16x16x32_bf16(a1, b, acc[1][f], 0, 0, 0);
        }
    }
#pragma unroll
    for (int ri = 0; ri < 2; ++ri)
#pragma unroll
        for (int r = 0; r < 4; ++r) {
            int row = r0 + 16 * ri + 4 * lq + r;
            if (row < N) {
#pragma unroll
                for (int f = 0; f < 8; ++f)
                    C[(size_t)row * 128 + 16 * f + li] = f2b(acc[ri][f][r]);
            }
        }
}

template <bool F32IN>
__global__ __launch_bounds__(TPB) void k_gemm(const void* __restrict__ Ain,
                                              const u16* __restrict__ Wt,
                                              u16* __restrict__ C, int N) {
    gemm_body<F32IN>(blockIdx.x, Ain, Wt, C, N);
}

// fused: blocks [0,nbG) run layer-1 GEMM (f32 input); blocks [nbG,..) run
// the CSR count+slot pass. The two are independent; the GEMM's MFMA work
// hides inside the atomic-latency window of countslot.
__global__ __launch_bounds__(TPB) void k_gemm1_count(const void* __restrict__ x,
                                                     const u16* __restrict__ Wt1,
                                                     u16* __restrict__ C, int N, int nbG,
                                                     const int* __restrict__ dst,
                                                     int* cnt, u16* __restrict__ aux, int E) {
    int b = blockIdx.x;
    if (b < nbG) {
        gemm_body<true>(b, x, Wt1, C, N);
    } else {
        countslot_body(b - nbG, dst, cnt, aux, E);
    }
}

// ------- aggregate: hout = relu(dinv_n^2*g[n] + sum coef*g[col] + b) -------
// 16 lanes/node. Per 64-edge supergroup: stage cols in regs (shfl source),
// issue chunk-0's 16 gathers immediately, compute dinv coefs while those are
// in flight, then per 16-edge chunk: one vmcnt(0) drain + consume.
__global__ __launch_bounds__(TPB) void k_agg(const u16* __restrict__ g,
                                             const u16* __restrict__ cols,
                                             const int* __restrict__ rowptr,
                                             const float* __restrict__ dinv,
                                             const float* __restrict__ bias,
                                             u16* __restrict__ hout, int N) {
    int node = blockIdx.x * 16 + (threadIdx.x >> 4);
    int lane = threadIdx.x & 15;
    if (node >= N) return;
    int beg = rowptr[node], end = rowptr[node + 1];
    float dn = dinv[node];
    float a[8];
    {   // self-loop term
        uint4 vs = *(const uint4*)(g + (size_t)node * 128 + lane * 8);
        float cs = dn * dn;
        a[0] = cs * b2f_lo(vs.x); a[1] = cs * b2f_hi(vs.x);
        a[2] = cs * b2f_lo(vs.y); a[3] = cs * b2f_hi(vs.y);
        a[4] = cs * b2f_lo(vs.z); a[5] = cs * b2f_hi(vs.z);
        a[6] = cs * b2f_lo(vs.w); a[7] = cs * b2f_hi(vs.w);
    }
    for (int sb = beg; sb < end; sb += 64) {
        int m = end - sb;
        if (m > 64) m = 64;
        // ---- stage cols for up to 64 edges (4 groups of 16 in regs) ----
        int cg[4];
#pragma unroll
        for (int q = 0; q < 4; ++q) {
            int off = 16 * q + lane;
            cg[q] = (off < m) ? (int)cols[sb + off] : node;  // masked: own row, coef 0
        }
        uint4 v[16];
        // ---- issue chunk 0 gathers before coef gathers (overlap windows) ----
#pragma unroll
        for (int u = 0; u < 16; ++u) {
            int col = __shfl(cg[0], u, 16);
            const u16* p = g + (size_t)col * 128 + lane * 8;
            asm volatile("global_load_dwordx4 %0, %1, off sc0"
                         : "=v"(v[u]) : "v"(p));
        }
        // ---- coefs (dinv gathers fly alongside chunk-0 data gathers) ----
        float cf4[4];
#pragma unroll
        for (int q = 0; q < 4; ++q) {
            int off = 16 * q + lane;
            cf4[q] = (off < m) ? dinv[cg[q]] * dn : 0.f;
        }
        // ---- chunk 0: drain + consume ----
        asm volatile("s_waitcnt vmcnt(0)" ::: "memory");
        __builtin_amdgcn_sched_barrier(0);
#pragma unroll
        for (int u = 0; u < 16; ++u) {
            float cf = __shfl(cf4[0], u, 16);
            a[0] += cf * b2f_lo(v[u].x); a[1] += cf * b2f_hi(v[u].x);
            a[2] += cf * b2f_lo(v[u].y); a[3] += cf * b2f_hi(v[u].y);
            a[4] += cf * b2f_lo(v[u].z); a[5] += cf * b2f_hi(v[u].z);
            a[6] += cf * b2f_lo(v[u].w); a[7] += cf * b2f_hi(v[u].w);
        }
        // ---- chunks 1..3 (only for rows past 16 edges in this group) ----
#pragma unroll
        for (int t = 1; t < 4; ++t) {
            if (16 * t < m) {
#pragma unroll
                for (int u = 0; u < 16; ++u) {
                    int col = __shfl(cg[t], u, 16);
                    const u16* p = g + (size_t)col * 128 + lane * 8;
                    asm volatile("global_load_dwordx4 %0, %1, off sc0"
                                 : "=v"(v[u]) : "v"(p));
                }
                asm volatile("s_waitcnt vmcnt(0)" ::: "memory");
                __builtin_amdgcn_sched_barrier(0);
#pragma unroll
                for (int u = 0; u < 16; ++u) {
                    float cf = __shfl(cf4[t], u, 16);
                    a[0] += cf * b2f_lo(v[u].x); a[1] += cf * b2f_hi(v[u].x);
                    a[2] += cf * b2f_lo(v[u].y); a[3] += cf * b2f_hi(v[u].y);
                    a[4] += cf * b2f_lo(v[u].z); a[5] += cf * b2f_hi(v[u].z);
                    a[6] += cf * b2f_lo(v[u].w); a[7] += cf * b2f_hi(v[u].w);
                }
            }
        }
    }
    const float4* bp = (const float4*)(bias + lane * 8);
    float4 b0 = bp[0], b1 = bp[1];
    a[0] = fmaxf(a[0] + b0.x, 0.f); a[1] = fmaxf(a[1] + b0.y, 0.f);
    a[2] = fmaxf(a[2] + b0.z, 0.f); a[3] = fmaxf(a[3] + b0.w, 0.f);
    a[4] = fmaxf(a[4] + b1.x, 0.f); a[5] = fmaxf(a[5] + b1.y, 0.f);
    a[6] = fmaxf(a[6] + b1.z, 0.f); a[7] = fmaxf(a[7] + b1.w, 0.f);
    uint4 o;
    o.x = (u32)f2b(a[0]) | ((u32)f2b(a[1]) << 16);
    o.y = (u32)f2b(a[2]) | ((u32)f2b(a[3]) << 16);
    o.z = (u32)f2b(a[4]) | ((u32)f2b(a[5]) << 16);
    o.w = (u32)f2b(a[6]) | ((u32)f2b(a[7]) << 16);
    *(uint4*)(hout + (size_t)node * 128 + lane * 8) = o;
}

// ---------------- pool (bounds fused: per-block binary search) ----------------
__global__ __launch_bounds__(128) void k_pool(const u16* __restrict__ h,
                                              const int* __restrict__ batch,
                                              float* __restrict__ out, int N, int G) {
    int g = blockIdx.x;
    int f = threadIdx.x;
    int beg, end;
    {
        int lo = 0, hi = N;
        while (lo < hi) { int m = (lo + hi) >> 1; if (batch[m] < g) lo = m + 1; else hi = m; }
        beg = lo;
        lo = 0; hi = N;
        int g1 = g + 1;
        while (lo < hi) { int m = (lo + hi) >> 1; if (batch[m] < g1) lo = m + 1; else hi = m; }
        end = lo;
    }
    float acc = 0.0f;
    for (int n = beg; n < end; ++n)
        acc += b2f_lo((u32)h[(size_t)n * 128 + f]);
    int c = end - beg; if (c < 1) c = 1;
    out[(size_t)g * 128 + f] = acc / (float)c;
}

extern "C" void kernel_launch(void* const* d_in, const int* in_sizes, int n_in,
                              void* d_out, int out_size, void* d_ws, size_t ws_size,
                              hipStream_t stream) {
    const float* x  = (const float*)d_in[0];
    const float* W1 = (const float*)d_in[2];
    const float* b1 = (const float*)d_in[3];
    const float* W2 = (const float*)d_in[4];
    const float* b2 = (const float*)d_in[5];
    const float* W3 = (const float*)d_in[6];
    const float* b3 = (const float*)d_in[7];
    const int* ei    = (const int*)d_in[8];
    const int* batch = (const int*)d_in[9];

    int N = in_sizes[0] / 128;
    int E = in_sizes[8] / 2;
    int G = out_size / 128;
    const int* src = ei;
    const int* dst = ei + E;

    char* w = (char*)d_ws;
    auto alloc = [&](size_t bytes) -> void* {
        void* p = (void*)w;
        w += (bytes + 255) & ~(size_t)255;
        return p;
    };
    int*   cnt    = (int*)alloc((size_t)N * 4);
    u16*   aux    = (u16*)alloc((size_t)E * 2);
    int*   rowptr = (int*)alloc((size_t)(N + 1) * 4);
    float* dinv   = (float*)alloc((size_t)N * 4);
    int*   bsum   = (int*)alloc(4096);
    u16*   cols   = (u16*)alloc((size_t)E * 2);
    u16*   Wt1    = (u16*)alloc(128 * 128 * 2);
    u16*   Wt2    = (u16*)alloc(128 * 128 * 2);
    u16*   Wt3    = (u16*)alloc(128 * 128 * 2);
    u16*   bufA   = (u16*)alloc((size_t)N * 128 * 2);
    u16*   bufB   = (u16*)alloc((size_t)N * 128 * 2);

    int nbN = (N + TPB - 1) / TPB;
    int nbE4 = (E / 4 + TPB - 1) / TPB;
    int nbG = (N + 127) / 128;
    int nbA = (N + 15) / 16;

    // ---- zero + weight prep (independent, fused) ----
    k_zero_prep<<<nbN + 24, TPB, 0, stream>>>(cnt, N, nbN, W1, W2, W3, Wt1, Wt2, Wt3);
    // ---- layer-1 GEMM overlapped with CSR count+slot ----
    k_gemm1_count<<<nbG + nbE4, TPB, 0, stream>>>(x, Wt1, bufA, N, nbG, dst, cnt, aux, E);
    // ---- rowptr scan + fill ----
    k_scan1<<<nbN, TPB, 0, stream>>>(cnt, rowptr, bsum, N);
    k_scan2<<<1, TPB, 0, stream>>>(bsum, nbN);
    k_scan3<<<nbN, TPB, 0, stream>>>(rowptr, bsum, cnt, dinv, N, E);
    k_fill<<<nbE4, TPB, 0, stream>>>(src, dst, rowptr, aux, cols, E);

    // ---- 3 GCN layers (layer-1 GEMM already done) ----
    k_agg<<<nbA, TPB, 0, stream>>>(bufA, cols, rowptr, dinv, b1, bufB, N);
    k_gemm<false><<<nbG, TPB, 0, stream>>>(bufB, Wt2, bufA, N);
    k_agg<<<nbA, TPB, 0, stream>>>(bufA, cols, rowptr, dinv, b2, bufB, N);
    k_gemm<false><<<nbG, TPB, 0, stream>>>(bufB, Wt3, bufA, N);
    k_agg<<<nbA, TPB, 0, stream>>>(bufA, cols, rowptr, dinv, b3, bufB, N);

    // ---- mean pool ----
    k_pool<<<G, 128, 0, stream>>>(bufB, batch, (float*)d_out, N, G);
}